// Round 3
// baseline (49.455 us; speedup 1.0000x reference)
//
#include <hip/hip_runtime.h>
#include <math.h>

#define LOG2E 1.44269504088896340736f

constexpr int IMG    = 64;                 // image stride (64x64)
constexpr int OW     = 62;                 // output width/height
constexpr int NPIX   = OW * OW;            // 3844
constexpr int D      = 32;
constexpr int K      = 4;
constexpr int CHUNKS = (NPIX + 63) / 64;   // 61
constexpr int TSTR   = 32;                 // floats per (k,d) table entry (128 B)

// Table layout per (k,d), stride 32 floats:
//   [0..7]   lr[8]   : log2(s1/s0) for binary features j in {0,1,2,3,5,6,7,8}
//   [8+2j]   Wc[j]   : -10*log2(e)*W1_j          (analog, j = 0..8)
//   [9+2j]   Q[j]    : exp(10*q1_j)
//   [26]     cB      : sum_j log2(s0_j) (+ log2(s1_4) for the forced center)
__global__ void build_table(const float* __restrict__ Wm,
                            const float* __restrict__ qm,
                            float* __restrict__ tb)
{
    const int t = threadIdx.x;      // t = k*32 + d
    if (t >= K * D) return;
    const int d = t & 31;
    const int k = t >> 5;
    const int base = d * 72;
    float* e = tb + t * TSTR;

    float cB = 0.f;
    int jj = 0;
    for (int j = 0; j < 9; ++j) {
        const float w0 = Wm[base + j * 4 + k];
        const float q0 = qm[base + j * 4 + k];
        const float s1 = 1.f / (1.f + expf(-10.f * (w0 - q0)));   // sigmoid(10(W-q))
        if (j == 4) {
            cB += log2f(s1);                 // center flag forced to 1
        } else {
            const float s0 = 1.f / (1.f + expf(10.f * q0));       // sigmoid(-10q)
            cB += log2f(s0);
            e[jj++] = log2f(s1) - log2f(s0); // lr
        }
        const float w1 = Wm[base + (9 + j) * 4 + k];
        const float q1 = qm[base + (9 + j) * 4 + k];
        e[8 + 2 * j]     = -10.f * LOG2E * w1;   // Wc
        e[8 + 2 * j + 1] = expf(10.f * q1);      // Q
    }
    e[26] = cB;
}

// One wave per (image, 64-pixel chunk, k). No LDS; constants via wave-uniform
// scalar loads from the precomputed table. menb accumulates in-register.
__global__ __launch_bounds__(64)
void orientation_main(const float* __restrict__ x,
                      const float* __restrict__ tb,
                      float* __restrict__ out)
{
    const int lane = threadIdx.x;
    int blk = blockIdx.x;
    const int k = blk & 3;                 // low bits: 4 k-waves share patch lines
    blk >>= 2;
    const int b     = blk / CHUNKS;
    const int chunk = blk - b * CHUNKS;

    const int pi    = chunk * 64 + lane;
    const bool valid = (pi < NPIX);
    const int pic   = valid ? pi : (NPIX - 1);
    const int row   = pic / OW;
    const int col   = pic - row * OW;

    // 3x3 patch + binary flags
    const float* xb = x + b * IMG * IMG;
    float p[9];
#pragma unroll
    for (int i = 0; i < 3; ++i)
#pragma unroll
        for (int jc = 0; jc < 3; ++jc)
            p[i * 3 + jc] = xb[(row + i) * IMG + col + jc];

    const float ctr = p[4];
    float x1v[9];
#pragma unroll
    for (int j = 0; j < 9; ++j)
        x1v[j] = (fabsf(p[j] - ctr) <= 3.0f) ? 1.f : 0.f;

    const float* tk = tb + (k * D) * TSTR;   // wave-uniform base

    float menb = 0.f;
#pragma unroll 4
    for (int d = 0; d < D; ++d) {
        const float* e = tk + d * TSTR;      // uniform -> s_load

        // binary product in log2 domain: every fma has exactly 1 SGPR operand
        float logB = e[26];
        logB = fmaf(x1v[0], e[0], logB);
        logB = fmaf(x1v[1], e[1], logB);
        logB = fmaf(x1v[2], e[2], logB);
        logB = fmaf(x1v[3], e[3], logB);
        logB = fmaf(x1v[5], e[4], logB);
        logB = fmaf(x1v[6], e[5], logB);
        logB = fmaf(x1v[7], e[6], logB);
        logB = fmaf(x1v[8], e[7], logB);

        // analog product: prodA = prod_j (1 + E_j*Q_j), E = exp2(p*Wc)
        float prodA = 1.f;
#pragma unroll
        for (int j = 0; j < 9; ++j) {
            const float E = __builtin_amdgcn_exp2f(p[j] * e[8 + 2 * j]);
            const float t = prodA * E;
            prodA = fmaf(t, e[9 + 2 * j], prodA);
        }

        menb = fmaf(__builtin_amdgcn_exp2f(logB),
                    __builtin_amdgcn_rcpf(prodA), menb);
    }

    float soma = __builtin_amdgcn_rcpf(
        1.f + __builtin_amdgcn_exp2f((0.5f - menb) * (10.f * LOG2E)));
    if (!valid) soma = 0.f;

#pragma unroll
    for (int m = 1; m <= 32; m <<= 1)
        soma += __shfl_xor(soma, m, 64);

    if (lane == 0)
        atomicAdd(&out[b * 4 + k], soma);
}

extern "C" void kernel_launch(void* const* d_in, const int* in_sizes, int n_in,
                              void* d_out, int out_size, void* d_ws, size_t ws_size,
                              hipStream_t stream) {
    const float* x  = (const float*)d_in[0];
    const float* Wm = (const float*)d_in[1];
    const float* qm = (const float*)d_in[2];
    float* out = (float*)d_out;
    float* tb  = (float*)d_ws;               // 4*32*32 floats = 16 KB

    const int B = in_sizes[0] / (IMG * IMG); // 16

    hipMemsetAsync(d_out, 0, (size_t)out_size * sizeof(float), stream);

    build_table<<<1, 128, 0, stream>>>(Wm, qm, tb);

    dim3 grid(B * CHUNKS * K);               // 16*61*4 = 3904 one-wave blocks
    dim3 block(64);
    orientation_main<<<grid, block, 0, stream>>>(x, tb, out);
}